// Round 1
// baseline (462.830 us; speedup 1.0000x reference)
//
#include <hip/hip_runtime.h>
#include <math.h>

namespace {

constexpr int kB = 16, kT = 32, kN = 64, kE = 64, kFIN = 2, kD = 64, kH = 4, kL = 2, kSH = 128;
constexpr int kG = kB * kT;    // 512 graphs
constexpr int kET = kE + kN;   // 128 edges incl. self loops

// ---------------- GAT LDS layout (float indices) ----------------
constexpr int HT = 0;                  // hT[64][65]  (transposed: hT[d*65+n])
constexpr int XL = HT + 64 * 65;       // xl[4][64][65]  (xl[h*4160 + n*65 + d])
constexpr int XR = XL + 4 * 64 * 65;   // xr[4][64][65]; later reused as tmp[64][65] + LN scratch
constexpr int LG = XR + 4 * 64 * 65;   // logitT[4][128]
constexpr int AL = LG + 4 * 128;       // alphaT[4][128]
constexpr int MB = AL + 4 * 128;       // mT[4][64]
constexpr int SB = MB + 4 * 64;        // 1/sum T[4][64]
constexpr int FEND = SB + 4 * 64;
// int section (indices into the int* base)
constexpr int ISRC = 0, IDST = 128, IOFF = 256, IEL = 321;
constexpr int NINT = IEL + 128;        // 449 ints
constexpr size_t GAT_LDS = size_t(FEND) * 4 + size_t(NINT) * 4;  // 157,700 B

// ---------------- LSTM LDS layout ----------------
constexpr int ES = 0;                  // embS[32][64]
constexpr int YS = ES + 32 * 64;       // ys[32][128]
constexpr int HB = YS + 32 * 128;      // h[128]
constexpr int CB = HB + 128;           // c[128]
constexpr int ZB = CB + 128;           // zbuf[512]
constexpr int ZX = ZB + 512;           // zx[32][512]
constexpr int LSTM_FLOATS = ZX + 32 * 512;
constexpr size_t LSTM_LDS = size_t(LSTM_FLOATS) * 4;  // 93,184 B

__device__ __forceinline__ float sigf(float v) { return 1.f / (1.f + expf(-v)); }

} // namespace

// =====================================================================
// GAT kernel: one block per graph, 512 threads (8 waves), 1 block/CU.
// =====================================================================
__global__ __launch_bounds__(512, 1)
void gat_kernel(const float* __restrict__ x, const int* __restrict__ eidx,
                const float* __restrict__ projW, const float* __restrict__ projb,
                const float* __restrict__ gWl, const float* __restrict__ gWr,
                const float* __restrict__ gatt, const float* __restrict__ gb,
                const float* __restrict__ lng, const float* __restrict__ lnb,
                float* __restrict__ emb)
{
    extern __shared__ float sm[];
    int* ib = (int*)(sm + FEND);
    const int g = blockIdx.x;
    const int t = threadIdx.x;

    // ---- edges + self loops (deterministic order) ----
    if (t < kET) {
        int s, d;
        if (t < kE) { s = eidx[g * 2 * kE + t]; d = eidx[g * 2 * kE + kE + t]; }
        else        { s = t - kE; d = s; }
        ib[ISRC + t] = s;
        ib[IDST + t] = d;
    }
    // ---- input projection + ReLU -> hT[d][n] ----
    #pragma unroll
    for (int r = 0; r < 8; ++r) {
        int p = t + 512 * r;
        int n = p >> 6, d = p & 63;
        float x0 = x[g * kN * kFIN + n * kFIN + 0];
        float x1 = x[g * kN * kFIN + n * kFIN + 1];
        float v = fmaf(x0, projW[d * kFIN + 0], fmaf(x1, projW[d * kFIN + 1], projb[d]));
        sm[HT + d * 65 + n] = fmaxf(v, 0.f);
    }
    __syncthreads();
    // ---- CSR build (deterministic, no atomics) ----
    if (t < kN) {
        int c = 0;
        for (int e = 0; e < kET; ++e) c += (ib[IDST + e] == t) ? 1 : 0;
        ib[IOFF + t + 1] = c;
    }
    __syncthreads();
    if (t == 0) {
        ib[IOFF + 0] = 0;
        for (int n = 0; n < kN; ++n) ib[IOFF + n + 1] += ib[IOFF + n];
    }
    __syncthreads();
    if (t < kN) {
        int pos = ib[IOFF + t];
        for (int e = 0; e < kET; ++e)
            if (ib[IDST + e] == t) ib[IEL + pos++] = e;
    }
    __syncthreads();

    for (int l = 0; l < kL; ++l) {
        // ---- xl = h@Wl^T, xr = h@Wr^T; thread owns (n, head, matrix) ----
        {
            const int n   = t & 63;
            const int grp = t >> 6;          // 0..7: 0-3 -> xl heads, 4-7 -> xr heads
            const int hh  = grp & 3;
            const float* W = ((grp < 4) ? gWl : gWr) + l * 256 * 64 + hh * 64 * 64;
            float* outp = sm + ((grp < 4) ? XL : XR) + hh * 4160 + n * 65;
            float hrow[64];
            #pragma unroll
            for (int k = 0; k < 64; ++k) hrow[k] = sm[HT + k * 65 + n];  // (k+n)%32 banks: free
            for (int dd = 0; dd < 64; ++dd) {
                const float4* w4 = (const float4*)(W + dd * 64);  // wave-uniform broadcast loads
                float acc = 0.f;
                #pragma unroll
                for (int k4 = 0; k4 < 16; ++k4) {
                    float4 w = w4[k4];
                    acc = fmaf(hrow[4 * k4 + 0], w.x, acc);
                    acc = fmaf(hrow[4 * k4 + 1], w.y, acc);
                    acc = fmaf(hrow[4 * k4 + 2], w.z, acc);
                    acc = fmaf(hrow[4 * k4 + 3], w.w, acc);
                }
                outp[dd] = acc;  // bank (n+dd)%32: conflict-free
            }
        }
        __syncthreads();
        // ---- edge logits: logitT[h][e] ----
        {
            const int e = t & 127, hh = t >> 7;
            const int s = ib[ISRC + e], d_ = ib[IDST + e];
            const float* av = gatt + (l * kH + hh) * kD;
            const float* pl = sm + XL + hh * 4160 + s * 65;
            const float* pr = sm + XR + hh * 4160 + d_ * 65;
            float acc = 0.f;
            #pragma unroll 8
            for (int dd = 0; dd < 64; ++dd) {
                float v = pl[dd] + pr[dd];
                v = (v > 0.f) ? v : 0.2f * v;       // leaky_relu 0.2
                acc = fmaf(av[dd], v, acc);
            }
            sm[LG + hh * 128 + e] = acc;
        }
        __syncthreads();
        // ---- segment max & sum over incoming edges ----
        if (t < 256) {
            const int n = t & 63, hh = t >> 6;
            const int i0 = ib[IOFF + n], i1 = ib[IOFF + n + 1];
            float m = -3.0e38f;
            for (int i = i0; i < i1; ++i) m = fmaxf(m, sm[LG + hh * 128 + ib[IEL + i]]);
            float ssum = 0.f;
            for (int i = i0; i < i1; ++i) ssum += expf(sm[LG + hh * 128 + ib[IEL + i]] - m);
            sm[MB + hh * 64 + n] = m;
            sm[SB + hh * 64 + n] = 1.f / ssum;
        }
        __syncthreads();
        // ---- alpha ----
        {
            const int e = t & 127, hh = t >> 7;
            const int d_ = ib[IDST + e];
            sm[AL + hh * 128 + e] =
                expf(sm[LG + hh * 128 + e] - sm[MB + hh * 64 + d_]) * sm[SB + hh * 64 + d_];
        }
        __syncthreads();
        // ---- aggregate + head-mean + bias -> tmp (reuses XR region; XR dead now) ----
        #pragma unroll
        for (int r = 0; r < 8; ++r) {
            int p = t + 512 * r;
            int n = p >> 6, dd = p & 63;
            const int i0 = ib[IOFF + n], i1 = ib[IOFF + n + 1];
            float acc = 0.f;
            for (int i = i0; i < i1; ++i) {
                int e = ib[IEL + i];
                int s = ib[ISRC + e];
                const float* xs = sm + XL + s * 65 + dd;
                acc = fmaf(sm[AL + 0 * 128 + e], xs[0 * 4160], acc);
                acc = fmaf(sm[AL + 1 * 128 + e], xs[1 * 4160], acc);
                acc = fmaf(sm[AL + 2 * 128 + e], xs[2 * 4160], acc);
                acc = fmaf(sm[AL + 3 * 128 + e], xs[3 * 4160], acc);
            }
            sm[XR + n * 65 + dd] = acc * 0.25f + gb[l * kD + dd];
        }
        __syncthreads();
        // ---- layernorm partials (scratch lives past tmp inside XR region) ----
        {
            const int n = t >> 3, q = t & 7;
            const float* row = sm + XR + n * 65 + q * 8;
            float s1 = 0.f, s2 = 0.f;
            #pragma unroll
            for (int i = 0; i < 8; ++i) { float v = row[i]; s1 += v; s2 = fmaf(v, v, s2); }
            sm[XR + 4160 + n * 8 + q]       = s1;
            sm[XR + 4160 + 512 + n * 8 + q] = s2;
        }
        __syncthreads();
        if (t < kN) {
            float s1 = 0.f, s2 = 0.f;
            #pragma unroll
            for (int q = 0; q < 8; ++q) {
                s1 += sm[XR + 4160 + t * 8 + q];
                s2 += sm[XR + 4160 + 512 + t * 8 + q];
            }
            float m  = s1 * (1.f / 64.f);
            float var = s2 * (1.f / 64.f) - m * m;
            sm[XR + 4160 + 1024 + t] = m;
            sm[XR + 4160 + 1088 + t] = rsqrtf(var + 1e-5f);
        }
        __syncthreads();
        // ---- apply LN + ReLU -> hT for next layer ----
        #pragma unroll
        for (int r = 0; r < 8; ++r) {
            int p = t + 512 * r;
            int n = p >> 6, dd = p & 63;
            float v  = sm[XR + n * 65 + dd];
            float mu = sm[XR + 4160 + 1024 + n];
            float rs = sm[XR + 4160 + 1088 + n];
            float y  = fmaf(lng[l * kD + dd] * (v - mu), rs, lnb[l * kD + dd]);
            sm[HT + dd * 65 + n] = fmaxf(y, 0.f);
        }
        __syncthreads();
    }
    // ---- global mean pool over nodes ----
    if (t < kD) {
        float s = 0.f;
        #pragma unroll 8
        for (int n = 0; n < kN; ++n) s += sm[HT + t * 65 + n];
        emb[g * kD + t] = s * (1.f / 64.f);
    }
}

// =====================================================================
// LSTM (2 layers, T=32) + MLP head: one block per batch element (16).
// Thread j owns z-row j; weight rows live in VGPRs across the t-loop.
// =====================================================================
__global__ __launch_bounds__(512, 1)
void lstm_head_kernel(const float* __restrict__ emb,
                      const float* __restrict__ W0ih, const float* __restrict__ W0hh,
                      const float* __restrict__ b0ih, const float* __restrict__ b0hh,
                      const float* __restrict__ W1ih, const float* __restrict__ W1hh,
                      const float* __restrict__ b1ih, const float* __restrict__ b1hh,
                      const float* __restrict__ hW1, const float* __restrict__ hb1,
                      const float* __restrict__ hW2, const float* __restrict__ hb2,
                      const float* __restrict__ hW3, const float* __restrict__ hb3,
                      float* __restrict__ outp)
{
    extern __shared__ float sm[];
    const int bb = blockIdx.x;
    const int j  = threadIdx.x;

    // stage this batch's emb rows into LDS (coalesced float4)
    ((float4*)(sm + ES))[j] = ((const float4*)(emb + bb * kT * kD))[j];
    if (j < kSH) { sm[HB + j] = 0.f; sm[CB + j] = 0.f; }
    __syncthreads();

    // ---- layer0 x-part: zx[t][j] = bias + W0ih[j,:]·emb[t,:] ----
    {
        float w[64];
        const float4* wr = (const float4*)(W0ih + j * 64);
        #pragma unroll
        for (int k4 = 0; k4 < 16; ++k4) {
            float4 v = wr[k4];
            w[4*k4+0] = v.x; w[4*k4+1] = v.y; w[4*k4+2] = v.z; w[4*k4+3] = v.w;
        }
        const float bias = b0ih[j] + b0hh[j];
        for (int tt = 0; tt < kT; ++tt) {
            const float4* ev = (const float4*)(sm + ES + tt * 64);
            float acc = bias;
            #pragma unroll
            for (int k4 = 0; k4 < 16; ++k4) {
                float4 e4 = ev[k4];
                acc = fmaf(w[4*k4+0], e4.x, acc); acc = fmaf(w[4*k4+1], e4.y, acc);
                acc = fmaf(w[4*k4+2], e4.z, acc); acc = fmaf(w[4*k4+3], e4.w, acc);
            }
            sm[ZX + tt * 512 + j] = acc;   // own column, no race
        }
    }
    __syncthreads();
    // ---- layer0 recurrence ----
    {
        float w[128];
        const float4* wr = (const float4*)(W0hh + j * 128);
        #pragma unroll
        for (int k4 = 0; k4 < 32; ++k4) {
            float4 v = wr[k4];
            w[4*k4+0] = v.x; w[4*k4+1] = v.y; w[4*k4+2] = v.z; w[4*k4+3] = v.w;
        }
        const int gate = j >> 7;  // 0:i 1:f 2:g 3:o
        for (int tt = 0; tt < kT; ++tt) {
            float acc = sm[ZX + tt * 512 + j];
            #pragma unroll
            for (int k4 = 0; k4 < 32; ++k4) {
                float4 h4 = ((const float4*)(sm + HB))[k4];   // broadcast
                acc = fmaf(w[4*k4+0], h4.x, acc); acc = fmaf(w[4*k4+1], h4.y, acc);
                acc = fmaf(w[4*k4+2], h4.z, acc); acc = fmaf(w[4*k4+3], h4.w, acc);
            }
            sm[ZB + j] = (gate == 2) ? tanhf(acc) : sigf(acc);
            __syncthreads();
            if (j < kSH) {
                float c = fmaf(sm[ZB + 128 + j], sm[CB + j], sm[ZB + j] * sm[ZB + 256 + j]);
                sm[CB + j] = c;
                float h = sm[ZB + 384 + j] * tanhf(c);
                sm[HB + j] = h;
                sm[YS + tt * 128 + j] = h;
            }
            __syncthreads();
        }
    }
    // ---- layer1 x-part: zx[t][j] = bias + W1ih[j,:]·ys[t,:] ----
    {
        float w[128];
        const float4* wr = (const float4*)(W1ih + j * 128);
        #pragma unroll
        for (int k4 = 0; k4 < 32; ++k4) {
            float4 v = wr[k4];
            w[4*k4+0] = v.x; w[4*k4+1] = v.y; w[4*k4+2] = v.z; w[4*k4+3] = v.w;
        }
        const float bias = b1ih[j] + b1hh[j];
        for (int tt = 0; tt < kT; ++tt) {
            float acc = bias;
            #pragma unroll
            for (int k4 = 0; k4 < 32; ++k4) {
                float4 y4 = ((const float4*)(sm + YS + tt * 128))[k4];
                acc = fmaf(w[4*k4+0], y4.x, acc); acc = fmaf(w[4*k4+1], y4.y, acc);
                acc = fmaf(w[4*k4+2], y4.z, acc); acc = fmaf(w[4*k4+3], y4.w, acc);
            }
            sm[ZX + tt * 512 + j] = acc;
        }
    }
    if (j < kSH) { sm[HB + j] = 0.f; sm[CB + j] = 0.f; }
    __syncthreads();
    // ---- layer1 recurrence (keep only final h) ----
    {
        float w[128];
        const float4* wr = (const float4*)(W1hh + j * 128);
        #pragma unroll
        for (int k4 = 0; k4 < 32; ++k4) {
            float4 v = wr[k4];
            w[4*k4+0] = v.x; w[4*k4+1] = v.y; w[4*k4+2] = v.z; w[4*k4+3] = v.w;
        }
        const int gate = j >> 7;
        for (int tt = 0; tt < kT; ++tt) {
            float acc = sm[ZX + tt * 512 + j];
            #pragma unroll
            for (int k4 = 0; k4 < 32; ++k4) {
                float4 h4 = ((const float4*)(sm + HB))[k4];
                acc = fmaf(w[4*k4+0], h4.x, acc); acc = fmaf(w[4*k4+1], h4.y, acc);
                acc = fmaf(w[4*k4+2], h4.z, acc); acc = fmaf(w[4*k4+3], h4.w, acc);
            }
            sm[ZB + j] = (gate == 2) ? tanhf(acc) : sigf(acc);
            __syncthreads();
            if (j < kSH) {
                float c = fmaf(sm[ZB + 128 + j], sm[CB + j], sm[ZB + j] * sm[ZB + 256 + j]);
                sm[CB + j] = c;
                sm[HB + j] = sm[ZB + 384 + j] * tanhf(c);
            }
            __syncthreads();
        }
    }
    // ---- MLP head ----
    if (j < 64) {
        float acc = hb1[j];
        #pragma unroll 4
        for (int k = 0; k < 128; ++k) acc = fmaf(hW1[j * 128 + k], sm[HB + k], acc);
        sm[ZB + j] = fmaxf(acc, 0.f);
    }
    __syncthreads();
    if (j < 32) {
        float acc = hb2[j];
        #pragma unroll 4
        for (int k = 0; k < 64; ++k) acc = fmaf(hW2[j * 64 + k], sm[ZB + k], acc);
        sm[ZB + 64 + j] = fmaxf(acc, 0.f);
    }
    __syncthreads();
    if (j == 0) {
        float acc = hb3[0];
        #pragma unroll
        for (int k = 0; k < 32; ++k) acc = fmaf(hW3[k], sm[ZB + 64 + k], acc);
        outp[bb] = sigf(acc);
    }
}

extern "C" void kernel_launch(void* const* d_in, const int* in_sizes, int n_in,
                              void* d_out, int out_size, void* d_ws, size_t ws_size,
                              hipStream_t stream) {
    const float* x     = (const float*)d_in[0];
    const int*   eidx  = (const int*)  d_in[1];
    const float* projW = (const float*)d_in[2];
    const float* projb = (const float*)d_in[3];
    const float* gWl   = (const float*)d_in[4];
    const float* gWr   = (const float*)d_in[5];
    const float* gatt  = (const float*)d_in[6];
    const float* gb    = (const float*)d_in[7];
    const float* lng   = (const float*)d_in[8];
    const float* lnb   = (const float*)d_in[9];
    const float* W0ih  = (const float*)d_in[10];
    const float* W0hh  = (const float*)d_in[11];
    const float* b0ih  = (const float*)d_in[12];
    const float* b0hh  = (const float*)d_in[13];
    const float* W1ih  = (const float*)d_in[14];
    const float* W1hh  = (const float*)d_in[15];
    const float* b1ih  = (const float*)d_in[16];
    const float* b1hh  = (const float*)d_in[17];
    const float* hW1   = (const float*)d_in[18];
    const float* hb1   = (const float*)d_in[19];
    const float* hW2   = (const float*)d_in[20];
    const float* hb2   = (const float*)d_in[21];
    const float* hW3   = (const float*)d_in[22];
    const float* hb3   = (const float*)d_in[23];
    float* outp = (float*)d_out;
    float* emb  = (float*)d_ws;   // [512][64] fp32 = 128 KB scratch

    // >64KB dynamic LDS opt-in (deterministic, not a stream op; capture-safe)
    (void)hipFuncSetAttribute((const void*)gat_kernel,
                              hipFuncAttributeMaxDynamicSharedMemorySize, (int)GAT_LDS);
    (void)hipFuncSetAttribute((const void*)lstm_head_kernel,
                              hipFuncAttributeMaxDynamicSharedMemorySize, (int)LSTM_LDS);

    hipLaunchKernelGGL(gat_kernel, dim3(kG), dim3(512), GAT_LDS, stream,
                       x, eidx, projW, projb, gWl, gWr, gatt, gb, lng, lnb, emb);
    hipLaunchKernelGGL(lstm_head_kernel, dim3(kB), dim3(512), LSTM_LDS, stream,
                       emb, W0ih, W0hh, b0ih, b0hh, W1ih, W1hh, b1ih, b1hh,
                       hW1, hb1, hW2, hb2, hW3, hb3, outp);
}